// Round 2
// baseline (7633.835 us; speedup 1.0000x reference)
//
#include <hip/hip_runtime.h>
#include <hip/hip_bf16.h>
#include <cmath>

typedef __hip_bfloat16 bf16;

#define B_   2
#define T_   2048
#define C_   2048
#define H_   16
#define HD_  128
#define RD_  64
#define QLR_ 1536
#define KLR_ 512
#define SCALE_ 0.07216878364870322f   // (128+64)^-0.5

static __device__ __forceinline__ float b2f(bf16 v){ return __bfloat162float(v); }
static __device__ __forceinline__ bf16  f2b(float v){ return __float2bfloat16(v); }
static __device__ __forceinline__ float us2f(unsigned short u){
    union { unsigned short s[2]; float f; } v; v.s[0]=0; v.s[1]=u; return v.f;
}
// runtime-dtype scalar load from a harness buffer
static __device__ __forceinline__ float ldS(const void* p, size_t i, int isf32){
    return isf32 ? ((const float*)p)[i] : b2f(((const bf16*)p)[i]);
}
// 4-wide contiguous load (i is a multiple of 4 at every call site)
static __device__ __forceinline__ void ld4(const void* p, size_t i, int isf32, float* o){
    if (isf32) {
        float4 v = *(const float4*)((const float*)p + i);
        o[0]=v.x; o[1]=v.y; o[2]=v.z; o[3]=v.w;
    } else {
        ushort4 u = *(const ushort4*)((const bf16*)p + i);
        o[0]=us2f(u.x); o[1]=us2f(u.y); o[2]=us2f(u.z); o[3]=us2f(u.w);
    }
}
// 4-wide contiguous store
static __device__ __forceinline__ void st4(void* p, size_t i, int isf32, const float* v){
    if (isf32) {
        *(float4*)((float*)p + i) = make_float4(v[0],v[1],v[2],v[3]);
    } else {
        bf16* q = (bf16*)p + i;
        q[0]=f2b(v[0]); q[1]=f2b(v[1]); q[2]=f2b(v[2]); q[3]=f2b(v[3]);
    }
}

// ---------------------------------------------------------------------------
// dtype detector: even-index 16-bit halves of x. bf16 data -> genuine N(0,1)
// values (exponent field small). f32 data -> low mantissa bits, uniform random
// -> ~47% decode to |v| >= 4096 (exp field >= 139). One wave.
// ---------------------------------------------------------------------------
__global__ __launch_bounds__(64) void detect_kernel(const unsigned short* __restrict__ x,
                                                    int* __restrict__ flag)
{
    int big = 0;
    for (int i = threadIdx.x; i < 1024; i += 64) {
        const unsigned short u = x[2*i];
        const int e = (u >> 7) & 0xFF;
        if (e >= 139) big++;
    }
    #pragma unroll
    for (int off = 32; off; off >>= 1) big += __shfl_down(big, off, 64);
    if (threadIdx.x == 0) *flag = (big > 8) ? 1 : 0;   // 1 = f32 harness
}

// ---------------------------------------------------------------------------
// Generic tiled GEMM: C[M,N] = A[M,K] @ B[K,N]; fp32 accumulate.
// A/B/C may be harness buffers (dtype per *flag if aH/bH/cH) or internal bf16.
// 64x64 tile, BK=16, 256 threads, 4x4 micro-tile per thread.
// ---------------------------------------------------------------------------
__global__ __launch_bounds__(256) void gemm_kernel(const void* __restrict__ A,
                                                   const void* __restrict__ Bm,
                                                   void* __restrict__ C,
                                                   int M, int N, int K,
                                                   const int* __restrict__ flag,
                                                   int aH, int bH, int cH)
{
    const int f  = *flag;
    const int af = aH ? f : 0;
    const int bf = bH ? f : 0;
    const int cf = cH ? f : 0;

    __shared__ float As[16][64];   // k-major: As[k][m]
    __shared__ float Bs[16][64];   // Bs[k][n]
    const int tid = threadIdx.x;
    const int bm  = blockIdx.y * 64;
    const int bn  = blockIdx.x * 64;
    const int tx  = tid & 15;      // n-dir group
    const int ty  = tid >> 4;      // m-dir group
    const int am  = tid >> 2;      // A-load row 0..63
    const int ak  = (tid & 3) << 2;// A-load k 0,4,8,12
    const int bk  = tid >> 4;      // B-load k 0..15
    const int bn4 = (tid & 15) << 2;

    float acc[4][4] = {};
    for (int kk = 0; kk < K; kk += 16) {
        float a[4], b[4];
        ld4(A,  (size_t)(bm + am) * K + kk + ak, af, a);
        ld4(Bm, (size_t)(kk + bk) * N + bn + bn4, bf, b);
        __syncthreads();
        As[ak+0][am]=a[0]; As[ak+1][am]=a[1]; As[ak+2][am]=a[2]; As[ak+3][am]=a[3];
        Bs[bk][bn4+0]=b[0]; Bs[bk][bn4+1]=b[1]; Bs[bk][bn4+2]=b[2]; Bs[bk][bn4+3]=b[3];
        __syncthreads();
        #pragma unroll
        for (int k = 0; k < 16; ++k) {
            float av[4], bv[4];
            *(float4*)av = *(const float4*)&As[k][ty<<2];
            *(float4*)bv = *(const float4*)&Bs[k][tx<<2];
            #pragma unroll
            for (int i = 0; i < 4; ++i)
                #pragma unroll
                for (int j = 0; j < 4; ++j)
                    acc[i][j] = fmaf(av[i], bv[j], acc[i][j]);
        }
    }
    #pragma unroll
    for (int i = 0; i < 4; ++i) {
        const int row = bm + (ty<<2) + i;
        st4(C, (size_t)row * N + bn + (tx<<2), cf, acc[i]);
    }
}

// ---------------------------------------------------------------------------
// In-place RMSNorm over rows of X [rows, NPER*256] (internal bf16); w harness.
// ---------------------------------------------------------------------------
template<int NPER>
__global__ __launch_bounds__(256) void rms_kernel(bf16* __restrict__ X,
                                                  const void* __restrict__ w,
                                                  const int* __restrict__ flag)
{
    const int wf = *flag;
    const int ncols = NPER * 256;
    __shared__ float red[4];
    const int row = blockIdx.x;
    const int tid = threadIdx.x;
    bf16* xr = X + (size_t)row * ncols;
    float vals[NPER];
    float ss = 0.f;
    #pragma unroll
    for (int i = 0; i < NPER; ++i) {
        float v = b2f(xr[tid + i*256]);
        vals[i] = v; ss += v*v;
    }
    #pragma unroll
    for (int off = 32; off; off >>= 1) ss += __shfl_down(ss, off, 64);
    if ((tid & 63) == 0) red[tid >> 6] = ss;
    __syncthreads();
    const float tot = red[0]+red[1]+red[2]+red[3];
    const float rs  = rsqrtf(tot / (float)ncols + 1e-6f);
    #pragma unroll
    for (int i = 0; i < NPER; ++i) {
        const int c = tid + i*256;
        xr[c] = f2b(vals[i] * rs * ldS(w, c, wf));
    }
}

// ---------------------------------------------------------------------------
// k_pe: in-place RMSNorm over 64 cols + RoPE. One 64-thread wave per row.
// ---------------------------------------------------------------------------
__global__ __launch_bounds__(64) void kpe_rms_rope(bf16* __restrict__ X,
                                                   const void* __restrict__ w,
                                                   const int* __restrict__ flag)
{
    const int wf   = *flag;
    const int row  = blockIdx.x;          // r = b*T + t
    const int t    = row & (T_ - 1);
    const int lane = threadIdx.x;         // 0..63
    bf16* xr = X + (size_t)row * RD_;
    const float v = b2f(xr[lane]);
    float ss = v * v;
    #pragma unroll
    for (int off = 32; off; off >>= 1) ss += __shfl_down(ss, off, 64);
    ss = __shfl(ss, 0, 64);
    const float rs = rsqrtf(ss / 64.f + 1e-6f);
    const float xn = v * rs * ldS(w, lane, wf);
    const int   i  = lane & 31;
    const float freq = powf(10000.f, -(float)(2*i) / 64.f);
    const float ang  = (float)t * freq;
    const float s = sinf(ang), c = cosf(ang);
    const float other = __shfl_xor(xn, 32, 64);
    // lane<32: out = x[i]*c - x[i+32]*s ; lane>=32: out = x[i-32]*s + x[i]*c
    const float o = (lane < 32) ? (xn * c - other * s) : (other * s + xn * c);
    xr[lane] = f2b(o);
}

// ---------------------------------------------------------------------------
// q_pe RoPE in-place: X [B*T, H*64] (internal bf16).
// ---------------------------------------------------------------------------
__global__ __launch_bounds__(256) void qpe_rope(bf16* __restrict__ X)
{
    const int row = blockIdx.x;
    const int t   = row & (T_ - 1);
    bf16* xr = X + (size_t)row * (H_ * RD_);
    const int tid = threadIdx.x;
    #pragma unroll
    for (int pp = 0; pp < 2; ++pp) {
        const int p  = tid + pp * 256;       // 0..511
        const int hh = p >> 5;
        const int i  = p & 31;
        const int i0 = hh * 64 + i;
        const int i1 = i0 + 32;
        const float x1 = b2f(xr[i0]), x2 = b2f(xr[i1]);
        const float freq = powf(10000.f, -(float)(2*i) / 64.f);
        const float ang  = (float)t * freq;
        const float s = sinf(ang), c = cosf(ang);
        xr[i0] = f2b(x1 * c - x2 * s);
        xr[i1] = f2b(x1 * s + x2 * c);
    }
}

// ---------------------------------------------------------------------------
// Causal attention, one (b,h,q-row) per block. Scores in LDS (<=2048).
// All operands are internal bf16 workspace buffers.
// ---------------------------------------------------------------------------
__global__ __launch_bounds__(256) void attn_kernel(const bf16* __restrict__ qnop,
                                                   const bf16* __restrict__ qpe,
                                                   const bf16* __restrict__ kv,
                                                   const bf16* __restrict__ kpe,
                                                   bf16* __restrict__ y)
{
    __shared__ float qs[192];
    __shared__ float ss[2048];
    __shared__ float red[4];
    __shared__ float red2[256];

    const int tq = blockIdx.x;
    const int h  = blockIdx.y;
    const int b  = blockIdx.z;
    const int r  = b * T_ + tq;
    const int tid  = threadIdx.x;
    const int wave = tid >> 6;
    const int lane = tid & 63;
    const int Lk   = tq + 1;

    for (int d = tid; d < 192; d += 256) {
        float v;
        if (d < 128) v = b2f(qnop[(size_t)r * (H_*128) + h*128 + d]);
        else         v = b2f(qpe [(size_t)r * (H_*64)  + h*64 + (d-128)]);
        qs[d] = v;
    }
    __syncthreads();

    // phase 1: scores
    for (int j = wave; j < Lk; j += 4) {
        const size_t rj = (size_t)(b * T_ + j);
        const bf16* krow = kv + rj * (H_*256) + h*128;
        float p = qs[lane]      * b2f(krow[lane])
                + qs[lane+64]   * b2f(krow[lane+64])
                + qs[lane+128]  * b2f(kpe[rj * RD_ + lane]);
        #pragma unroll
        for (int off = 32; off; off >>= 1) p += __shfl_down(p, off, 64);
        if (lane == 0) ss[j] = p * SCALE_;
    }
    __syncthreads();

    // phase 2: softmax
    float m = -1e30f;
    for (int j = tid; j < Lk; j += 256) m = fmaxf(m, ss[j]);
    #pragma unroll
    for (int off = 32; off; off >>= 1) m = fmaxf(m, __shfl_down(m, off, 64));
    if (lane == 0) red[wave] = m;
    __syncthreads();
    m = fmaxf(fmaxf(red[0], red[1]), fmaxf(red[2], red[3]));
    float sum = 0.f;
    for (int j = tid; j < Lk; j += 256) {
        const float p = __expf(ss[j] - m);
        ss[j] = p;
        sum += p;
    }
    #pragma unroll
    for (int off = 32; off; off >>= 1) sum += __shfl_down(sum, off, 64);
    __syncthreads();                 // all reads of red (max) done
    if (lane == 0) red[wave] = sum;
    __syncthreads();
    const float inv = 1.f / (red[0] + red[1] + red[2] + red[3]);

    // phase 3: y[d] = sum_j p[j] * v[j][d]
    const int d    = tid & 127;
    const int half = tid >> 7;
    float acc = 0.f;
    for (int j = half; j < Lk; j += 2) {
        acc += ss[j] * b2f(kv[(size_t)(b*T_ + j) * (H_*256) + H_*128 + h*128 + d]);
    }
    red2[tid] = acc;
    __syncthreads();
    if (tid < 128) {
        const float o = (red2[tid] + red2[tid + 128]) * inv;
        y[(size_t)r * (H_*128) + h*128 + d] = f2b(o);
    }
}

// ---------------------------------------------------------------------------
extern "C" void kernel_launch(void* const* d_in, const int* in_sizes, int n_in,
                              void* d_out, int out_size, void* d_ws, size_t ws_size,
                              hipStream_t stream)
{
    const void* x         = d_in[0];
    const void* Wq_down   = d_in[1];
    const void* q_norm_w  = d_in[2];
    const void* Wq_up     = d_in[3];
    const void* Wq_pe     = d_in[4];
    const void* Wkv_down  = d_in[5];
    const void* kv_norm_w = d_in[6];
    const void* Wkv_up    = d_in[7];
    const void* Wk_pe     = d_in[8];
    const void* kpe_nw    = d_in[9];
    const void* Wo        = d_in[10];

    const int M = B_ * T_;   // 4096 rows
    char* ws = (char*)d_ws;
    // workspace layout (bytes)
    bf16* cQ   = (bf16*)(ws + 0);          // [4096,1536] 12,582,912 B
    bf16* cKV  = (bf16*)(ws + 12582912);   // [4096, 512]  4,194,304 B
    bf16* kpeb = (bf16*)(ws + 16777216);   // [4096,  64]    524,288 B
    bf16* qnop = (bf16*)(ws + 17301504);   // [4096,2048] 16,777,216 B
    bf16* qpeb = (bf16*)(ws + 34078720);   // [4096,1024]  8,388,608 B
    bf16* kvb  = (bf16*)(ws + 42467328);   // [4096,4096] 33,554,432 B
    bf16* yb   = (bf16*)(ws + 76021760);   // [4096,2048] 16,777,216 B
    int*  flag = (int*)(ws + 92798976);    // 4 B (end 92,798,980)

    const dim3 blk(256);

    detect_kernel<<<1, dim3(64), 0, stream>>>((const unsigned short*)x, flag);

    // Q path: x @ Wq_down -> cQ ; rms in place
    gemm_kernel<<<dim3(QLR_/64, M/64), blk, 0, stream>>>(x, Wq_down, cQ, M, QLR_, C_, flag, 1, 1, 0);
    rms_kernel<6><<<M, blk, 0, stream>>>(cQ, q_norm_w, flag);
    // KV path: x @ Wkv_down -> cKV ; rms in place
    gemm_kernel<<<dim3(KLR_/64, M/64), blk, 0, stream>>>(x, Wkv_down, cKV, M, KLR_, C_, flag, 1, 1, 0);
    rms_kernel<2><<<M, blk, 0, stream>>>(cKV, kv_norm_w, flag);
    // k_pe: x @ Wk_pe -> kpeb ; rms + rope in place
    gemm_kernel<<<dim3(RD_/64, M/64), blk, 0, stream>>>(x, Wk_pe, kpeb, M, RD_, C_, flag, 1, 1, 0);
    kpe_rms_rope<<<M, dim3(64), 0, stream>>>(kpeb, kpe_nw, flag);
    // q up-projections
    gemm_kernel<<<dim3((H_*HD_)/64, M/64), blk, 0, stream>>>(cQ, Wq_up, qnop, M, H_*HD_, QLR_, flag, 0, 1, 0);
    gemm_kernel<<<dim3((H_*RD_)/64, M/64), blk, 0, stream>>>(cQ, Wq_pe, qpeb, M, H_*RD_, QLR_, flag, 0, 1, 0);
    qpe_rope<<<M, blk, 0, stream>>>(qpeb);
    // kv up-projection (k_nop | v)
    gemm_kernel<<<dim3((H_*2*HD_)/64, M/64), blk, 0, stream>>>(cKV, Wkv_up, kvb, M, H_*2*HD_, KLR_, flag, 0, 1, 0);
    // attention
    attn_kernel<<<dim3(T_, H_, B_), blk, 0, stream>>>(qnop, qpeb, kvb, kpeb, yb);
    // output projection -> d_out (dtype per flag)
    gemm_kernel<<<dim3(C_/64, M/64), blk, 0, stream>>>(yb, Wo, d_out, M, C_, H_*HD_, flag, 0, 1, 1);
}

// Round 3
// 2148.172 us; speedup vs baseline: 3.5536x; 3.5536x over previous
//
#include <hip/hip_runtime.h>
#include <hip/hip_bf16.h>
#include <cmath>

typedef __hip_bfloat16 bf16;
typedef __attribute__((ext_vector_type(8))) short s16x8;
typedef __attribute__((ext_vector_type(4))) float f32x4;

#define B_   2
#define T_   2048
#define C_   2048
#define H_   16
#define HD_  128
#define RD_  64
#define QLR_ 1536
#define KLR_ 512
#define SCALE_ 0.07216878364870322f   // (128+64)^-0.5

static __device__ __forceinline__ float b2f(bf16 v){ return __bfloat162float(v); }
static __device__ __forceinline__ bf16  f2b(float v){ return __float2bfloat16(v); }
static __device__ __forceinline__ float us2f(unsigned short u){
    union { unsigned short s[2]; float f; } v; v.s[0]=0; v.s[1]=u; return v.f;
}
static __device__ __forceinline__ float ldS(const void* p, size_t i, int isf32){
    return isf32 ? ((const float*)p)[i] : b2f(((const bf16*)p)[i]);
}
static __device__ __forceinline__ void ld4(const void* p, size_t i, int isf32, float* o){
    if (isf32) {
        float4 v = *(const float4*)((const float*)p + i);
        o[0]=v.x; o[1]=v.y; o[2]=v.z; o[3]=v.w;
    } else {
        ushort4 u = *(const ushort4*)((const bf16*)p + i);
        o[0]=us2f(u.x); o[1]=us2f(u.y); o[2]=us2f(u.z); o[3]=us2f(u.w);
    }
}
static __device__ __forceinline__ void st4(void* p, size_t i, int isf32, const float* v){
    if (isf32) {
        *(float4*)((float*)p + i) = make_float4(v[0],v[1],v[2],v[3]);
    } else {
        bf16* q = (bf16*)p + i;
        q[0]=f2b(v[0]); q[1]=f2b(v[1]); q[2]=f2b(v[2]); q[3]=f2b(v[3]);
    }
}

// ---------------------------------------------------------------------------
// dtype detector (1 = harness buffers are f32, 0 = bf16)
// ---------------------------------------------------------------------------
__global__ __launch_bounds__(64) void detect_kernel(const unsigned short* __restrict__ x,
                                                    int* __restrict__ flag)
{
    int big = 0;
    for (int i = threadIdx.x; i < 1024; i += 64) {
        const unsigned short u = x[2*i];
        const int e = (u >> 7) & 0xFF;
        if (e >= 139) big++;
    }
    #pragma unroll
    for (int off = 32; off; off >>= 1) big += __shfl_down(big, off, 64);
    if (threadIdx.x == 0) *flag = (big > 8) ? 1 : 0;
}

// ---------------------------------------------------------------------------
// Generic tiled GEMM (fp32 VALU): C[M,N] = A[M,K] @ B[K,N]
// ---------------------------------------------------------------------------
__global__ __launch_bounds__(256) void gemm_kernel(const void* __restrict__ A,
                                                   const void* __restrict__ Bm,
                                                   void* __restrict__ C,
                                                   int M, int N, int K,
                                                   const int* __restrict__ flag,
                                                   int aH, int bH, int cH)
{
    const int f  = *flag;
    const int af = aH ? f : 0;
    const int bf = bH ? f : 0;
    const int cf = cH ? f : 0;

    __shared__ float As[16][64];
    __shared__ float Bs[16][64];
    const int tid = threadIdx.x;
    const int bm  = blockIdx.y * 64;
    const int bn  = blockIdx.x * 64;
    const int tx  = tid & 15;
    const int ty  = tid >> 4;
    const int am  = tid >> 2;
    const int ak  = (tid & 3) << 2;
    const int bk  = tid >> 4;
    const int bn4 = (tid & 15) << 2;

    float acc[4][4] = {};
    for (int kk = 0; kk < K; kk += 16) {
        float a[4], b[4];
        ld4(A,  (size_t)(bm + am) * K + kk + ak, af, a);
        ld4(Bm, (size_t)(kk + bk) * N + bn + bn4, bf, b);
        __syncthreads();
        As[ak+0][am]=a[0]; As[ak+1][am]=a[1]; As[ak+2][am]=a[2]; As[ak+3][am]=a[3];
        Bs[bk][bn4+0]=b[0]; Bs[bk][bn4+1]=b[1]; Bs[bk][bn4+2]=b[2]; Bs[bk][bn4+3]=b[3];
        __syncthreads();
        #pragma unroll
        for (int k = 0; k < 16; ++k) {
            float av[4], bv[4];
            *(float4*)av = *(const float4*)&As[k][ty<<2];
            *(float4*)bv = *(const float4*)&Bs[k][tx<<2];
            #pragma unroll
            for (int i = 0; i < 4; ++i)
                #pragma unroll
                for (int j = 0; j < 4; ++j)
                    acc[i][j] = fmaf(av[i], bv[j], acc[i][j]);
        }
    }
    #pragma unroll
    for (int i = 0; i < 4; ++i) {
        const int row = bm + (ty<<2) + i;
        st4(C, (size_t)row * N + bn + (tx<<2), cf, acc[i]);
    }
}

// ---------------------------------------------------------------------------
// In-place RMSNorm over rows of X [rows, NPER*256] (internal bf16)
// ---------------------------------------------------------------------------
template<int NPER>
__global__ __launch_bounds__(256) void rms_kernel(bf16* __restrict__ X,
                                                  const void* __restrict__ w,
                                                  const int* __restrict__ flag)
{
    const int wf = *flag;
    const int ncols = NPER * 256;
    __shared__ float red[4];
    const int row = blockIdx.x;
    const int tid = threadIdx.x;
    bf16* xr = X + (size_t)row * ncols;
    float vals[NPER];
    float ss = 0.f;
    #pragma unroll
    for (int i = 0; i < NPER; ++i) {
        float v = b2f(xr[tid + i*256]);
        vals[i] = v; ss += v*v;
    }
    #pragma unroll
    for (int off = 32; off; off >>= 1) ss += __shfl_down(ss, off, 64);
    if ((tid & 63) == 0) red[tid >> 6] = ss;
    __syncthreads();
    const float tot = red[0]+red[1]+red[2]+red[3];
    const float rs  = rsqrtf(tot / (float)ncols + 1e-6f);
    #pragma unroll
    for (int i = 0; i < NPER; ++i) {
        const int c = tid + i*256;
        xr[c] = f2b(vals[i] * rs * ldS(w, c, wf));
    }
}

// ---------------------------------------------------------------------------
// k_pe: in-place RMSNorm over 64 cols + RoPE
// ---------------------------------------------------------------------------
__global__ __launch_bounds__(64) void kpe_rms_rope(bf16* __restrict__ X,
                                                   const void* __restrict__ w,
                                                   const int* __restrict__ flag)
{
    const int wf   = *flag;
    const int row  = blockIdx.x;
    const int t    = row & (T_ - 1);
    const int lane = threadIdx.x;
    bf16* xr = X + (size_t)row * RD_;
    const float v = b2f(xr[lane]);
    float ss = v * v;
    #pragma unroll
    for (int off = 32; off; off >>= 1) ss += __shfl_down(ss, off, 64);
    ss = __shfl(ss, 0, 64);
    const float rs = rsqrtf(ss / 64.f + 1e-6f);
    const float xn = v * rs * ldS(w, lane, wf);
    const int   i  = lane & 31;
    const float freq = powf(10000.f, -(float)(2*i) / 64.f);
    const float ang  = (float)t * freq;
    const float s = sinf(ang), c = cosf(ang);
    const float other = __shfl_xor(xn, 32, 64);
    const float o = (lane < 32) ? (xn * c - other * s) : (other * s + xn * c);
    xr[lane] = f2b(o);
}

// ---------------------------------------------------------------------------
// q_pe RoPE in-place: X [B*T, H*64]
// ---------------------------------------------------------------------------
__global__ __launch_bounds__(256) void qpe_rope(bf16* __restrict__ X)
{
    const int row = blockIdx.x;
    const int t   = row & (T_ - 1);
    bf16* xr = X + (size_t)row * (H_ * RD_);
    const int tid = threadIdx.x;
    #pragma unroll
    for (int pp = 0; pp < 2; ++pp) {
        const int p  = tid + pp * 256;
        const int hh = p >> 5;
        const int i  = p & 31;
        const int i0 = hh * 64 + i;
        const int i1 = i0 + 32;
        const float x1 = b2f(xr[i0]), x2 = b2f(xr[i1]);
        const float freq = powf(10000.f, -(float)(2*i) / 64.f);
        const float ang  = (float)t * freq;
        const float s = sinf(ang), c = cosf(ang);
        xr[i0] = f2b(x1 * c - x2 * s);
        xr[i1] = f2b(x1 * s + x2 * c);
    }
}

// ---------------------------------------------------------------------------
// Flash-style MFMA attention.
// Block = 64 q-rows of one (b,h); 4 waves x 16 rows; k-tiles of 64.
// qnop [B*T, H*128], qpe [B*T, H*64] (roped), kv [B*T, H*256] (k_nop | v),
// kpe [B*T, 64] (normed+roped), y [B*T, H*128].
// MFMA 16x16x32 bf16 layouts (HW-verified, learn_hip m89/m120):
//   A[m=lane&15][k=quad*8+j], B[k=quad*8+j][n=lane&15],
//   C/D: col=lane&15, row=quad*4+reg.
// ---------------------------------------------------------------------------
__global__ __launch_bounds__(256) void flash_attn(const bf16* __restrict__ qnop,
                                                  const bf16* __restrict__ qpe,
                                                  const bf16* __restrict__ kv,
                                                  const bf16* __restrict__ kpe,
                                                  bf16* __restrict__ y)
{
    // padded LDS: row strides 200/72 halfwords -> bank stride 4 (2-way, free)
    __shared__ __align__(16) short Klds[64][200];   // [krow][dim0..191]
    __shared__ __align__(16) short Vt[128][72];     // [vdim][krow]
    __shared__ __align__(16) short Plds[4][16][72]; // per-wave P [qrow][krow]

    const int qt  = (int)gridDim.x - 1 - (int)blockIdx.x;  // heavy blocks first
    const int h   = blockIdx.y;
    const int b   = blockIdx.z;
    const int q0  = qt * 64;
    const int tid = threadIdx.x;
    const int w    = tid >> 6;
    const int lane = tid & 63;
    const int quad = lane >> 4;
    const int l16  = lane & 15;
    const int row0 = q0 + w * 16;          // wave's first q row

    // ---- Q fragments (A-layout), loaded once ----
    s16x8 aq[6];
    {
        const size_t r = (size_t)(b * T_ + row0 + l16);
        const bf16* qn = qnop + r * (H_*128) + h*128 + quad*8;
        #pragma unroll
        for (int kk = 0; kk < 4; ++kk) aq[kk] = *(const s16x8*)(qn + kk*32);
        const bf16* qp = qpe + r * (H_*64) + h*64 + quad*8;
        aq[4] = *(const s16x8*)(qp);
        aq[5] = *(const s16x8*)(qp + 32);
    }

    f32x4 o[8];
    #pragma unroll
    for (int i = 0; i < 8; ++i) o[i] = (f32x4){0.f,0.f,0.f,0.f};
    float m_run[4] = {-1e30f,-1e30f,-1e30f,-1e30f};
    float l_run[4] = {0.f,0.f,0.f,0.f};

    const int ntiles = qt + 1;
    for (int it = 0; it < ntiles; ++it) {
        const int j0 = it * 64;
        __syncthreads();   // previous tile's compute done before restage

        // ---- stage K-tile: k_nop (64x128) ----
        #pragma unroll
        for (int c = 0; c < 4; ++c) {
            const int e   = c*256 + tid;       // 0..1023
            const int row = e >> 4;
            const int ch  = e & 15;
            const uint4 v = *(const uint4*)(kv + (size_t)(b*T_ + j0 + row) * (H_*256) + h*128 + ch*8);
            *(uint4*)&Klds[row][ch*8] = v;
        }
        // ---- stage K-tile: k_pe (64x64) ----
        #pragma unroll
        for (int c = 0; c < 2; ++c) {
            const int e   = c*256 + tid;       // 0..511
            const int row = e >> 3;
            const int ch  = e & 7;
            const uint4 v = *(const uint4*)(kpe + (size_t)(b*T_ + j0 + row) * RD_ + ch*8);
            *(uint4*)&Klds[row][128 + ch*8] = v;
        }
        // ---- stage V-tile transposed: Vt[dim][row] ----
        #pragma unroll
        for (int c = 0; c < 8; ++c) {
            const int e   = c*256 + tid;       // 0..2047
            const int row = e & 63;
            const int d4  = (e >> 6) * 4;
            const ushort4 v = *(const ushort4*)(kv + (size_t)(b*T_ + j0 + row) * (H_*256) + H_*128 + h*128 + d4);
            Vt[d4+0][row] = (short)v.x;
            Vt[d4+1][row] = (short)v.y;
            Vt[d4+2][row] = (short)v.z;
            Vt[d4+3][row] = (short)v.w;
        }
        __syncthreads();

        if (j0 <= row0 + 15) {                 // wave has unmasked work
            const bool needmask = (j0 + 63 > row0);
            // ---- S = Q K^T (16x64 per wave) ----
            f32x4 s[4];
            #pragma unroll
            for (int nsub = 0; nsub < 4; ++nsub) {
                f32x4 acc = (f32x4){0.f,0.f,0.f,0.f};
                #pragma unroll
                for (int kk = 0; kk < 6; ++kk) {
                    const s16x8 bk = *(const s16x8*)&Klds[nsub*16 + l16][kk*32 + quad*8];
                    acc = __builtin_amdgcn_mfma_f32_16x16x32_bf16(aq[kk], bk, acc, 0, 0, 0);
                }
                #pragma unroll
                for (int reg = 0; reg < 4; ++reg) acc[reg] *= SCALE_;
                s[nsub] = acc;
            }
            if (needmask) {
                #pragma unroll
                for (int nsub = 0; nsub < 4; ++nsub)
                    #pragma unroll
                    for (int reg = 0; reg < 4; ++reg) {
                        const int col = j0 + nsub*16 + l16;
                        const int row = row0 + quad*4 + reg;
                        if (col > row) s[nsub][reg] = -1e30f;
                    }
            }
            // ---- online softmax (row spread over 16 lanes sharing quad) ----
            float mt[4], alpha[4], rs[4];
            #pragma unroll
            for (int reg = 0; reg < 4; ++reg)
                mt[reg] = fmaxf(fmaxf(s[0][reg], s[1][reg]), fmaxf(s[2][reg], s[3][reg]));
            #pragma unroll
            for (int d = 1; d < 16; d <<= 1)
                #pragma unroll
                for (int reg = 0; reg < 4; ++reg)
                    mt[reg] = fmaxf(mt[reg], __shfl_xor(mt[reg], d, 64));
            #pragma unroll
            for (int reg = 0; reg < 4; ++reg) {
                const float mnew = fmaxf(m_run[reg], mt[reg]);
                alpha[reg] = __expf(m_run[reg] - mnew);
                m_run[reg] = mnew;
                rs[reg] = 0.f;
            }
            #pragma unroll
            for (int nsub = 0; nsub < 4; ++nsub)
                #pragma unroll
                for (int reg = 0; reg < 4; ++reg) {
                    const float p = __expf(s[nsub][reg] - m_run[reg]);
                    s[nsub][reg] = p;
                    rs[reg] += p;
                }
            #pragma unroll
            for (int d = 1; d < 16; d <<= 1)
                #pragma unroll
                for (int reg = 0; reg < 4; ++reg)
                    rs[reg] += __shfl_xor(rs[reg], d, 64);
            #pragma unroll
            for (int reg = 0; reg < 4; ++reg)
                l_run[reg] = l_run[reg] * alpha[reg] + rs[reg];

            // ---- P -> LDS (C-layout -> A-layout round trip) ----
            #pragma unroll
            for (int nsub = 0; nsub < 4; ++nsub)
                #pragma unroll
                for (int reg = 0; reg < 4; ++reg)
                    Plds[w][quad*4 + reg][nsub*16 + l16] = *(short*)&((bf16&)(*(bf16[1]){f2b(s[nsub][reg])}));
            // rescale O
            #pragma unroll
            for (int n2 = 0; n2 < 8; ++n2)
                #pragma unroll
                for (int reg = 0; reg < 4; ++reg)
                    o[n2][reg] *= alpha[reg];

            // ---- O += P V ----
            const s16x8 ap0 = *(const s16x8*)&Plds[w][l16][quad*8];
            const s16x8 ap1 = *(const s16x8*)&Plds[w][l16][32 + quad*8];
            #pragma unroll
            for (int n2 = 0; n2 < 8; ++n2) {
                const s16x8 bv0 = *(const s16x8*)&Vt[n2*16 + l16][quad*8];
                const s16x8 bv1 = *(const s16x8*)&Vt[n2*16 + l16][32 + quad*8];
                o[n2] = __builtin_amdgcn_mfma_f32_16x16x32_bf16(ap0, bv0, o[n2], 0, 0, 0);
                o[n2] = __builtin_amdgcn_mfma_f32_16x16x32_bf16(ap1, bv1, o[n2], 0, 0, 0);
            }
        }
    }

    // ---- normalize + store ----
    #pragma unroll
    for (int reg = 0; reg < 4; ++reg) {
        const float inv = 1.f / l_run[reg];
        const size_t r = (size_t)(b*T_ + row0 + quad*4 + reg);
        bf16* yr = y + r * (H_*128) + h*128 + l16;
        #pragma unroll
        for (int n2 = 0; n2 < 8; ++n2)
            yr[n2*16] = f2b(o[n2][reg] * inv);
    }
}

// ---------------------------------------------------------------------------
extern "C" void kernel_launch(void* const* d_in, const int* in_sizes, int n_in,
                              void* d_out, int out_size, void* d_ws, size_t ws_size,
                              hipStream_t stream)
{
    const void* x         = d_in[0];
    const void* Wq_down   = d_in[1];
    const void* q_norm_w  = d_in[2];
    const void* Wq_up     = d_in[3];
    const void* Wq_pe     = d_in[4];
    const void* Wkv_down  = d_in[5];
    const void* kv_norm_w = d_in[6];
    const void* Wkv_up    = d_in[7];
    const void* Wk_pe     = d_in[8];
    const void* kpe_nw    = d_in[9];
    const void* Wo        = d_in[10];

    const int M = B_ * T_;   // 4096 rows
    char* ws = (char*)d_ws;
    bf16* cQ   = (bf16*)(ws + 0);          // [4096,1536]
    bf16* cKV  = (bf16*)(ws + 12582912);   // [4096, 512]
    bf16* kpeb = (bf16*)(ws + 16777216);   // [4096,  64]
    bf16* qnop = (bf16*)(ws + 17301504);   // [4096,2048]
    bf16* qpeb = (bf16*)(ws + 34078720);   // [4096,1024]
    bf16* kvb  = (bf16*)(ws + 42467328);   // [4096,4096]
    bf16* yb   = (bf16*)(ws + 76021760);   // [4096,2048]
    int*  flag = (int*)(ws + 92798976);    // 4 B

    const dim3 blk(256);

    detect_kernel<<<1, dim3(64), 0, stream>>>((const unsigned short*)x, flag);

    gemm_kernel<<<dim3(QLR_/64, M/64), blk, 0, stream>>>(x, Wq_down, cQ, M, QLR_, C_, flag, 1, 1, 0);
    rms_kernel<6><<<M, blk, 0, stream>>>(cQ, q_norm_w, flag);
    gemm_kernel<<<dim3(KLR_/64, M/64), blk, 0, stream>>>(x, Wkv_down, cKV, M, KLR_, C_, flag, 1, 1, 0);
    rms_kernel<2><<<M, blk, 0, stream>>>(cKV, kv_norm_w, flag);
    gemm_kernel<<<dim3(RD_/64, M/64), blk, 0, stream>>>(x, Wk_pe, kpeb, M, RD_, C_, flag, 1, 1, 0);
    kpe_rms_rope<<<M, dim3(64), 0, stream>>>(kpeb, kpe_nw, flag);
    gemm_kernel<<<dim3((H_*HD_)/64, M/64), blk, 0, stream>>>(cQ, Wq_up, qnop, M, H_*HD_, QLR_, flag, 0, 1, 0);
    gemm_kernel<<<dim3((H_*RD_)/64, M/64), blk, 0, stream>>>(cQ, Wq_pe, qpeb, M, H_*RD_, QLR_, flag, 0, 1, 0);
    qpe_rope<<<M, blk, 0, stream>>>(qpeb);
    gemm_kernel<<<dim3((H_*2*HD_)/64, M/64), blk, 0, stream>>>(cKV, Wkv_up, kvb, M, H_*2*HD_, KLR_, flag, 0, 1, 0);
    flash_attn<<<dim3(T_/64, H_, B_), blk, 0, stream>>>(qnop, qpeb, kvb, kpeb, yb);
    gemm_kernel<<<dim3(C_/64, M/64), blk, 0, stream>>>(yb, Wo, d_out, M, C_, H_*HD_, flag, 0, 1, 1);
}

// Round 4
// 716.407 us; speedup vs baseline: 10.6557x; 2.9985x over previous
//
#include <hip/hip_runtime.h>
#include <hip/hip_bf16.h>
#include <cmath>

typedef __hip_bfloat16 bf16;
typedef __attribute__((ext_vector_type(8))) short s16x8;
typedef __attribute__((ext_vector_type(4))) float f32x4;

#define B_   2
#define T_   2048
#define C_   2048
#define H_   16
#define HD_  128
#define RD_  64
#define QLR_ 1536
#define KLR_ 512
#define SCALE_ 0.07216878364870322f   // (128+64)^-0.5

static __device__ __forceinline__ float b2f(bf16 v){ return __bfloat162float(v); }
static __device__ __forceinline__ bf16  f2b(float v){ return __float2bfloat16(v); }
static __device__ __forceinline__ float us2f(unsigned short u){
    union { unsigned short s[2]; float f; } v; v.s[0]=0; v.s[1]=u; return v.f;
}
static __device__ __forceinline__ float ldS(const void* p, size_t i, int isf32){
    return isf32 ? ((const float*)p)[i] : b2f(((const bf16*)p)[i]);
}
static __device__ __forceinline__ void ld4(const void* p, size_t i, int isf32, float* o){
    if (isf32) {
        float4 v = *(const float4*)((const float*)p + i);
        o[0]=v.x; o[1]=v.y; o[2]=v.z; o[3]=v.w;
    } else {
        ushort4 u = *(const ushort4*)((const bf16*)p + i);
        o[0]=us2f(u.x); o[1]=us2f(u.y); o[2]=us2f(u.z); o[3]=us2f(u.w);
    }
}

// ---------------------------------------------------------------------------
// dtype detector (1 = harness buffers are f32, 0 = bf16)
// ---------------------------------------------------------------------------
__global__ __launch_bounds__(64) void detect_kernel(const unsigned short* __restrict__ x,
                                                    int* __restrict__ flag)
{
    int big = 0;
    for (int i = threadIdx.x; i < 1024; i += 64) {
        const unsigned short u = x[2*i];
        const int e = (u >> 7) & 0xFF;
        if (e >= 139) big++;
    }
    #pragma unroll
    for (int off = 32; off; off >>= 1) big += __shfl_down(big, off, 64);
    if (threadIdx.x == 0) *flag = (big > 8) ? 1 : 0;
}

// ---------------------------------------------------------------------------
// Elementwise convert harness buffer -> bf16 (8 elems/thread)
// ---------------------------------------------------------------------------
__global__ __launch_bounds__(256) void convert_kernel(const void* __restrict__ in,
                                                      bf16* __restrict__ out, int n,
                                                      const int* __restrict__ flag)
{
    const int f = *flag;
    const int i0 = (blockIdx.x * 256 + threadIdx.x) * 8;
    if (i0 >= n) return;
    float v[8];
    ld4(in, i0, f, v);
    ld4(in, i0 + 4, f, v + 4);
    bf16* o = out + i0;
    #pragma unroll
    for (int k = 0; k < 8; ++k) o[k] = f2b(v[k]);
}

// ---------------------------------------------------------------------------
// Transpose harness weight [R][Cc] -> bf16 out [Cc][R] (row stride R)
// ---------------------------------------------------------------------------
__global__ __launch_bounds__(256) void transpose_kernel(const void* __restrict__ in,
                                                        bf16* __restrict__ out,
                                                        int R, int Cc,
                                                        const int* __restrict__ flag)
{
    const int f = *flag;
    __shared__ float tile[32][33];
    const int c0 = blockIdx.x * 32, r0 = blockIdx.y * 32;
    const int tx = threadIdx.x & 31, ty = threadIdx.x >> 5;  // 32 x 8
    #pragma unroll
    for (int i = 0; i < 4; ++i)
        tile[ty + 8*i][tx] = ldS(in, (size_t)(r0 + ty + 8*i) * Cc + c0 + tx, f);
    __syncthreads();
    #pragma unroll
    for (int i = 0; i < 4; ++i)
        out[(size_t)(c0 + ty + 8*i) * R + r0 + tx] = f2b(tile[tx][ty + 8*i]);
}

// ---------------------------------------------------------------------------
// MFMA GEMM: C[M,N] = A[M,K] @ BT[N,K]^T. A,BT bf16; C bf16 or f32 (cf).
// 128x128 tile, BK=32, 4 waves (2x2), 4x4 16x16x32 frags per wave.
// Staging via global_load_lds width=16; LDS [row][32] unpadded (frag reads
// are permuted-contiguous 1KB windows -> conflict-free).
// M mult of 128, K mult of 32; N guarded at store (BT rows padded to grid).
// ---------------------------------------------------------------------------
__global__ __launch_bounds__(256) void mfma_gemm(const bf16* __restrict__ A,
                                                 const bf16* __restrict__ BT,
                                                 void* __restrict__ C,
                                                 int N, int K,
                                                 const int* __restrict__ flag, int cH)
{
    const int cf = cH ? *flag : 0;
    __shared__ bf16 As[128 * 32];
    __shared__ bf16 Bs[128 * 32];
    const int tid  = threadIdx.x;
    const int w    = tid >> 6;
    const int lane = tid & 63;
    const int quad = lane >> 4;
    const int l16  = lane & 15;
    const int wm   = w >> 1, wn = w & 1;
    const int bm   = blockIdx.y * 128, bn = blockIdx.x * 128;
    const int lrow = lane >> 2;        // 0..15
    const int lk   = (lane & 3) * 8;   // k-offset in elements

    f32x4 acc[4][4];
    #pragma unroll
    for (int i = 0; i < 4; ++i)
        #pragma unroll
        for (int j = 0; j < 4; ++j)
            acc[i][j] = (f32x4){0.f, 0.f, 0.f, 0.f};

    for (int kk = 0; kk < K; kk += 32) {
        if (kk) __syncthreads();   // prior frag reads done before restage
        #pragma unroll
        for (int c = 0; c < 2; ++c) {
            const int ch  = w * 2 + c;            // 0..7 (wave-uniform)
            const int row = ch * 16 + lrow;
            const bf16* g = A + (size_t)(bm + row) * K + kk + lk;
            __builtin_amdgcn_global_load_lds(
                (const __attribute__((address_space(1))) unsigned int*)g,
                (__attribute__((address_space(3))) unsigned int*)(As + ch * 512),
                16, 0, 0);
        }
        #pragma unroll
        for (int c = 0; c < 2; ++c) {
            const int ch  = w * 2 + c;
            const int row = ch * 16 + lrow;
            const bf16* g = BT + (size_t)(bn + row) * K + kk + lk;
            __builtin_amdgcn_global_load_lds(
                (const __attribute__((address_space(1))) unsigned int*)g,
                (__attribute__((address_space(3))) unsigned int*)(Bs + ch * 512),
                16, 0, 0);
        }
        __syncthreads();           // drains vmcnt (incl. global_load_lds)

        s16x8 af[4], bfv[4];
        #pragma unroll
        for (int i = 0; i < 4; ++i)
            af[i] = *(const s16x8*)&As[(wm*64 + i*16 + l16) * 32 + quad*8];
        #pragma unroll
        for (int j = 0; j < 4; ++j)
            bfv[j] = *(const s16x8*)&Bs[(wn*64 + j*16 + l16) * 32 + quad*8];
        #pragma unroll
        for (int i = 0; i < 4; ++i)
            #pragma unroll
            for (int j = 0; j < 4; ++j)
                acc[i][j] = __builtin_amdgcn_mfma_f32_16x16x32_bf16(af[i], bfv[j], acc[i][j], 0, 0, 0);
    }

    #pragma unroll
    for (int i = 0; i < 4; ++i) {
        const int crow = bm + wm*64 + i*16 + quad*4;
        #pragma unroll
        for (int r = 0; r < 4; ++r) {
            #pragma unroll
            for (int j = 0; j < 4; ++j) {
                const int ccol = bn + wn*64 + j*16 + l16;
                if (ccol < N) {
                    const size_t idx = (size_t)(crow + r) * N + ccol;
                    if (cf) ((float*)C)[idx] = acc[i][j][r];
                    else    ((bf16*)C)[idx] = f2b(acc[i][j][r]);
                }
            }
        }
    }
}

// ---------------------------------------------------------------------------
// In-place RMSNorm over rows of X [rows, NPER*256] (internal bf16)
// ---------------------------------------------------------------------------
template<int NPER>
__global__ __launch_bounds__(256) void rms_kernel(bf16* __restrict__ X,
                                                  const void* __restrict__ w,
                                                  const int* __restrict__ flag)
{
    const int wf = *flag;
    const int ncols = NPER * 256;
    __shared__ float red[4];
    const int row = blockIdx.x;
    const int tid = threadIdx.x;
    bf16* xr = X + (size_t)row * ncols;
    float vals[NPER];
    float ss = 0.f;
    #pragma unroll
    for (int i = 0; i < NPER; ++i) {
        float v = b2f(xr[tid + i*256]);
        vals[i] = v; ss += v*v;
    }
    #pragma unroll
    for (int off = 32; off; off >>= 1) ss += __shfl_down(ss, off, 64);
    if ((tid & 63) == 0) red[tid >> 6] = ss;
    __syncthreads();
    const float tot = red[0]+red[1]+red[2]+red[3];
    const float rs  = rsqrtf(tot / (float)ncols + 1e-6f);
    #pragma unroll
    for (int i = 0; i < NPER; ++i) {
        const int c = tid + i*256;
        xr[c] = f2b(vals[i] * rs * ldS(w, c, wf));
    }
}

// ---------------------------------------------------------------------------
// k_pe: in-place RMSNorm over 64 cols + RoPE
// ---------------------------------------------------------------------------
__global__ __launch_bounds__(64) void kpe_rms_rope(bf16* __restrict__ X,
                                                   const void* __restrict__ w,
                                                   const int* __restrict__ flag)
{
    const int wf   = *flag;
    const int row  = blockIdx.x;
    const int t    = row & (T_ - 1);
    const int lane = threadIdx.x;
    bf16* xr = X + (size_t)row * RD_;
    const float v = b2f(xr[lane]);
    float ss = v * v;
    #pragma unroll
    for (int off = 32; off; off >>= 1) ss += __shfl_down(ss, off, 64);
    ss = __shfl(ss, 0, 64);
    const float rs = rsqrtf(ss / 64.f + 1e-6f);
    const float xn = v * rs * ldS(w, lane, wf);
    const int   i  = lane & 31;
    const float freq = powf(10000.f, -(float)(2*i) / 64.f);
    const float ang  = (float)t * freq;
    const float s = sinf(ang), c = cosf(ang);
    const float other = __shfl_xor(xn, 32, 64);
    const float o = (lane < 32) ? (xn * c - other * s) : (other * s + xn * c);
    xr[lane] = f2b(o);
}

// ---------------------------------------------------------------------------
// q_pe RoPE in-place: X [B*T, H*64]
// ---------------------------------------------------------------------------
__global__ __launch_bounds__(256) void qpe_rope(bf16* __restrict__ X)
{
    const int row = blockIdx.x;
    const int t   = row & (T_ - 1);
    bf16* xr = X + (size_t)row * (H_ * RD_);
    const int tid = threadIdx.x;
    #pragma unroll
    for (int pp = 0; pp < 2; ++pp) {
        const int p  = tid + pp * 256;
        const int hh = p >> 5;
        const int i  = p & 31;
        const int i0 = hh * 64 + i;
        const int i1 = i0 + 32;
        const float x1 = b2f(xr[i0]), x2 = b2f(xr[i1]);
        const float freq = powf(10000.f, -(float)(2*i) / 64.f);
        const float ang  = (float)t * freq;
        const float s = sinf(ang), c = cosf(ang);
        xr[i0] = f2b(x1 * c - x2 * s);
        xr[i1] = f2b(x1 * s + x2 * c);
    }
}

// ---------------------------------------------------------------------------
// Flash-style MFMA attention (unchanged from R3, passing).
// ---------------------------------------------------------------------------
__global__ __launch_bounds__(256) void flash_attn(const bf16* __restrict__ qnop,
                                                  const bf16* __restrict__ qpe,
                                                  const bf16* __restrict__ kv,
                                                  const bf16* __restrict__ kpe,
                                                  bf16* __restrict__ y)
{
    __shared__ __align__(16) short Klds[64][200];
    __shared__ __align__(16) short Vt[128][72];
    __shared__ __align__(16) short Plds[4][16][72];

    const int qt  = (int)gridDim.x - 1 - (int)blockIdx.x;
    const int h   = blockIdx.y;
    const int b   = blockIdx.z;
    const int q0  = qt * 64;
    const int tid = threadIdx.x;
    const int w    = tid >> 6;
    const int lane = tid & 63;
    const int quad = lane >> 4;
    const int l16  = lane & 15;
    const int row0 = q0 + w * 16;

    s16x8 aq[6];
    {
        const size_t r = (size_t)(b * T_ + row0 + l16);
        const bf16* qn = qnop + r * (H_*128) + h*128 + quad*8;
        #pragma unroll
        for (int kk = 0; kk < 4; ++kk) aq[kk] = *(const s16x8*)(qn + kk*32);
        const bf16* qp = qpe + r * (H_*64) + h*64 + quad*8;
        aq[4] = *(const s16x8*)(qp);
        aq[5] = *(const s16x8*)(qp + 32);
    }

    f32x4 o[8];
    #pragma unroll
    for (int i = 0; i < 8; ++i) o[i] = (f32x4){0.f,0.f,0.f,0.f};
    float m_run[4] = {-1e30f,-1e30f,-1e30f,-1e30f};
    float l_run[4] = {0.f,0.f,0.f,0.f};

    const int ntiles = qt + 1;
    for (int it = 0; it < ntiles; ++it) {
        const int j0 = it * 64;
        __syncthreads();

        #pragma unroll
        for (int c = 0; c < 4; ++c) {
            const int e   = c*256 + tid;
            const int row = e >> 4;
            const int ch  = e & 15;
            const uint4 v = *(const uint4*)(kv + (size_t)(b*T_ + j0 + row) * (H_*256) + h*128 + ch*8);
            *(uint4*)&Klds[row][ch*8] = v;
        }
        #pragma unroll
        for (int c = 0; c < 2; ++c) {
            const int e   = c*256 + tid;
            const int row = e >> 3;
            const int ch  = e & 7;
            const uint4 v = *(const uint4*)(kpe + (size_t)(b*T_ + j0 + row) * RD_ + ch*8);
            *(uint4*)&Klds[row][128 + ch*8] = v;
        }
        #pragma unroll
        for (int c = 0; c < 8; ++c) {
            const int e   = c*256 + tid;
            const int row = e & 63;
            const int d4  = (e >> 6) * 4;
            const ushort4 v = *(const ushort4*)(kv + (size_t)(b*T_ + j0 + row) * (H_*256) + H_*128 + h*128 + d4);
            Vt[d4+0][row] = (short)v.x;
            Vt[d4+1][row] = (short)v.y;
            Vt[d4+2][row] = (short)v.z;
            Vt[d4+3][row] = (short)v.w;
        }
        __syncthreads();

        if (j0 <= row0 + 15) {
            const bool needmask = (j0 + 63 > row0);
            f32x4 s[4];
            #pragma unroll
            for (int nsub = 0; nsub < 4; ++nsub) {
                f32x4 acc = (f32x4){0.f,0.f,0.f,0.f};
                #pragma unroll
                for (int kk = 0; kk < 6; ++kk) {
                    const s16x8 bk = *(const s16x8*)&Klds[nsub*16 + l16][kk*32 + quad*8];
                    acc = __builtin_amdgcn_mfma_f32_16x16x32_bf16(aq[kk], bk, acc, 0, 0, 0);
                }
                #pragma unroll
                for (int reg = 0; reg < 4; ++reg) acc[reg] *= SCALE_;
                s[nsub] = acc;
            }
            if (needmask) {
                #pragma unroll
                for (int nsub = 0; nsub < 4; ++nsub)
                    #pragma unroll
                    for (int reg = 0; reg < 4; ++reg) {
                        const int col = j0 + nsub*16 + l16;
                        const int row = row0 + quad*4 + reg;
                        if (col > row) s[nsub][reg] = -1e30f;
                    }
            }
            float mt[4], alpha[4], rs[4];
            #pragma unroll
            for (int reg = 0; reg < 4; ++reg)
                mt[reg] = fmaxf(fmaxf(s[0][reg], s[1][reg]), fmaxf(s[2][reg], s[3][reg]));
            #pragma unroll
            for (int d = 1; d < 16; d <<= 1)
                #pragma unroll
                for (int reg = 0; reg < 4; ++reg)
                    mt[reg] = fmaxf(mt[reg], __shfl_xor(mt[reg], d, 64));
            #pragma unroll
            for (int reg = 0; reg < 4; ++reg) {
                const float mnew = fmaxf(m_run[reg], mt[reg]);
                alpha[reg] = __expf(m_run[reg] - mnew);
                m_run[reg] = mnew;
                rs[reg] = 0.f;
            }
            #pragma unroll
            for (int nsub = 0; nsub < 4; ++nsub)
                #pragma unroll
                for (int reg = 0; reg < 4; ++reg) {
                    const float p = __expf(s[nsub][reg] - m_run[reg]);
                    s[nsub][reg] = p;
                    rs[reg] += p;
                }
            #pragma unroll
            for (int d = 1; d < 16; d <<= 1)
                #pragma unroll
                for (int reg = 0; reg < 4; ++reg)
                    rs[reg] += __shfl_xor(rs[reg], d, 64);
            #pragma unroll
            for (int reg = 0; reg < 4; ++reg)
                l_run[reg] = l_run[reg] * alpha[reg] + rs[reg];

            #pragma unroll
            for (int nsub = 0; nsub < 4; ++nsub)
                #pragma unroll
                for (int reg = 0; reg < 4; ++reg)
                    Plds[w][quad*4 + reg][nsub*16 + l16] = *(short*)&((bf16&)(*(bf16[1]){f2b(s[nsub][reg])}));
            #pragma unroll
            for (int n2 = 0; n2 < 8; ++n2)
                #pragma unroll
                for (int reg = 0; reg < 4; ++reg)
                    o[n2][reg] *= alpha[reg];

            const s16x8 ap0 = *(const s16x8*)&Plds[w][l16][quad*8];
            const s16x8 ap1 = *(const s16x8*)&Plds[w][l16][32 + quad*8];
            #pragma unroll
            for (int n2 = 0; n2 < 8; ++n2) {
                const s16x8 bv0 = *(const s16x8*)&Vt[n2*16 + l16][quad*8];
                const s16x8 bv1 = *(const s16x8*)&Vt[n2*16 + l16][32 + quad*8];
                o[n2] = __builtin_amdgcn_mfma_f32_16x16x32_bf16(ap0, bv0, o[n2], 0, 0, 0);
                o[n2] = __builtin_amdgcn_mfma_f32_16x16x32_bf16(ap1, bv1, o[n2], 0, 0, 0);
            }
        }
    }

    #pragma unroll
    for (int reg = 0; reg < 4; ++reg) {
        const float inv = 1.f / l_run[reg];
        const size_t r = (size_t)(b*T_ + row0 + quad*4 + reg);
        bf16* yr = y + r * (H_*128) + h*128 + l16;
        #pragma unroll
        for (int n2 = 0; n2 < 8; ++n2)
            yr[n2*16] = f2b(o[n2][reg] * inv);
    }
}

// ---------------------------------------------------------------------------
extern "C" void kernel_launch(void* const* d_in, const int* in_sizes, int n_in,
                              void* d_out, int out_size, void* d_ws, size_t ws_size,
                              hipStream_t stream)
{
    const void* x         = d_in[0];
    const void* Wq_down   = d_in[1];
    const void* q_norm_w  = d_in[2];
    const void* Wq_up     = d_in[3];
    const void* Wq_pe     = d_in[4];
    const void* Wkv_down  = d_in[5];
    const void* kv_norm_w = d_in[6];
    const void* Wkv_up    = d_in[7];
    const void* Wk_pe     = d_in[8];
    const void* kpe_nw    = d_in[9];
    const void* Wo        = d_in[10];

    char* ws = (char*)d_ws;
    // workspace layout (bytes); weights rotate through one 6.29 MB pool
    int*  flag = (int*)(ws + 0);
    bf16* xb   = (bf16*)(ws + 256);        // [4096,2048] 16,777,216
    bf16* cQ   = (bf16*)(ws + 16777472);   // [4096,1536] 12,582,912
    bf16* cKV  = (bf16*)(ws + 29360384);   // [4096, 512]  4,194,304
    bf16* kpeb = (bf16*)(ws + 33554688);   // [4096,  64]    524,288
    bf16* qnop = (bf16*)(ws + 34078976);   // [4096,2048] 16,777,216
    bf16* qpeb = (bf16*)(ws + 50856192);   // [4096,1024]  8,388,608
    bf16* kvb  = (bf16*)(ws + 59244800);   // [4096,4096] 33,554,432
    bf16* yb   = (bf16*)(ws + 92799232);   // [4096,2048] 16,777,216
    bf16* Wt   = (bf16*)(ws + 109576448);  // pool, max 6,291,456 (end ~115.9 MB)

    const dim3 blk(256);

    detect_kernel<<<1, dim3(64), 0, stream>>>((const unsigned short*)x, flag);
    convert_kernel<<<(B_*T_*C_)/(256*8), blk, 0, stream>>>(x, xb, B_*T_*C_, flag);

    // ---- Q down: x @ Wq_down -> cQ ; rms ----
    transpose_kernel<<<dim3(QLR_/32, C_/32), blk, 0, stream>>>(Wq_down, Wt, C_, QLR_, flag);
    mfma_gemm<<<dim3(QLR_/128, 32), blk, 0, stream>>>(xb, Wt, cQ, QLR_, C_, flag, 0);
    rms_kernel<6><<<B_*T_, blk, 0, stream>>>(cQ, q_norm_w, flag);

    // ---- KV down: x @ Wkv_down -> cKV ; rms ----
    transpose_kernel<<<dim3(KLR_/32, C_/32), blk, 0, stream>>>(Wkv_down, Wt, C_, KLR_, flag);
    mfma_gemm<<<dim3(KLR_/128, 32), blk, 0, stream>>>(xb, Wt, cKV, KLR_, C_, flag, 0);
    rms_kernel<2><<<B_*T_, blk, 0, stream>>>(cKV, kv_norm_w, flag);

    // ---- k_pe: x @ Wk_pe -> kpeb ; rms+rope (BT padded to 128 rows) ----
    transpose_kernel<<<dim3(RD_/32, C_/32), blk, 0, stream>>>(Wk_pe, Wt, C_, RD_, flag);
    mfma_gemm<<<dim3(1, 32), blk, 0, stream>>>(xb, Wt, kpeb, RD_, C_, flag, 0);
    kpe_rms_rope<<<B_*T_, dim3(64), 0, stream>>>(kpeb, kpe_nw, flag);

    // ---- q up-projections ----
    transpose_kernel<<<dim3((H_*HD_)/32, QLR_/32), blk, 0, stream>>>(Wq_up, Wt, QLR_, H_*HD_, flag);
    mfma_gemm<<<dim3((H_*HD_)/128, 32), blk, 0, stream>>>(cQ, Wt, qnop, H_*HD_, QLR_, flag, 0);
    transpose_kernel<<<dim3((H_*RD_)/32, QLR_/32), blk, 0, stream>>>(Wq_pe, Wt, QLR_, H_*RD_, flag);
    mfma_gemm<<<dim3((H_*RD_)/128, 32), blk, 0, stream>>>(cQ, Wt, qpeb, H_*RD_, QLR_, flag, 0);
    qpe_rope<<<B_*T_, blk, 0, stream>>>(qpeb);

    // ---- kv up-projection ----
    transpose_kernel<<<dim3((H_*2*HD_)/32, KLR_/32), blk, 0, stream>>>(Wkv_up, Wt, KLR_, H_*2*HD_, flag);
    mfma_gemm<<<dim3((H_*2*HD_)/128, 32), blk, 0, stream>>>(cKV, Wt, kvb, H_*2*HD_, KLR_, flag, 0);

    // ---- attention ----
    flash_attn<<<dim3(T_/64, H_, B_), blk, 0, stream>>>(qnop, qpeb, kvb, kpeb, yb);

    // ---- output projection (dtype of d_out per flag) ----
    transpose_kernel<<<dim3(C_/32, (H_*HD_)/32), blk, 0, stream>>>(Wo, Wt, H_*HD_, C_, flag);
    mfma_gemm<<<dim3(C_/128, 32), blk, 0, stream>>>(yb, Wt, d_out, C_, H_*HD_, flag, 1);
}